// Round 7
// baseline (674.524 us; speedup 1.0000x reference)
//
#include <hip/hip_runtime.h>
#include <hip/hip_bf16.h>

#define N_NODES 100000
#define N_EDGES 1600000
#define D_IN 64
#define D_OUT 64
#define E_DIM 32
#define KCAT 288            // 3*64 (S buckets) + 3*32 (T buckets)
#define NK (4 * N_NODES)    // sort keys: 4*dst + etype (slot 3 unused -> count 0)
#define NBCHUNK 391         // ceil(NK / 1024)

typedef unsigned long long u64;
typedef __hip_bfloat16 bf16;
typedef unsigned char u8;
typedef float __attribute__((ext_vector_type(4))) f32x4;   // native vec for nontemporal builtins

// ---------------------------------------------------------------------------
// zero helper (capture-safe)
// ---------------------------------------------------------------------------
__global__ __launch_bounds__(256) void zero_buf(float4* __restrict__ p, long n4) {
    long i = (long)blockIdx.x * 256 + threadIdx.x;
    long stride = (long)gridDim.x * 256;
    float4 z = make_float4(0.f, 0.f, 0.f, 0.f);
    for (; i < n4; i += stride) p[i] = z;
}

// ---------------------------------------------------------------------------
// K1: xout[n] = nf[n] @ W_node[ntype[n]]  (wave/node, grid-strided, bf16 out)
// ---------------------------------------------------------------------------
__global__ __launch_bounds__(256) void node_xform(const float* __restrict__ nf,
                                                  const float* __restrict__ Wn,
                                                  const int* __restrict__ ntype,
                                                  bf16* __restrict__ xout) {
    __shared__ float wl[2 * 64 * 64];   // 32 KB
    for (int i = threadIdx.x; i < 2 * 64 * 64; i += 256) wl[i] = Wn[i];
    __syncthreads();
    int wid = threadIdx.x >> 6, lane = threadIdx.x & 63;
    int gw = blockIdx.x * 4 + wid, nw = gridDim.x * 4;
    for (int n = gw; n < N_NODES; n += nw) {
        int t = ntype[n];                          // wave-uniform
        float x = nf[(size_t)n * 64 + lane];
        const float* wcol = &wl[t * 4096 + lane];
        float acc = 0.f;
#pragma unroll
        for (int k = 0; k < 64; ++k)
            acc = fmaf(__shfl(x, k), wcol[k * 64], acc);
        xout[(size_t)n * 64 + lane] = __float2bfloat16(acc);
    }
}

// ---------------------------------------------------------------------------
// count + rank: rank[i] = arrival order within key (4*dst+etype).
// Key multiplicity is Poisson(5.3) -> u8 cannot overflow (max ~40).
// ---------------------------------------------------------------------------
__global__ __launch_bounds__(256) void count_rank(const int* __restrict__ eidx,
                                                  const int* __restrict__ etype,
                                                  int* __restrict__ cnt,
                                                  u8* __restrict__ rank) {
    int i = blockIdx.x * 256 + threadIdx.x;   // edge quad id
    if (i >= N_EDGES / 4) return;
    int4 d = ((const int4*)(eidx + N_EDGES))[i];
    int4 t = ((const int4*)etype)[i];
    int r0 = atomicAdd(&cnt[4 * d.x + t.x], 1);
    int r1 = atomicAdd(&cnt[4 * d.y + t.y], 1);
    int r2 = atomicAdd(&cnt[4 * d.z + t.z], 1);
    int r3 = atomicAdd(&cnt[4 * d.w + t.w], 1);
    uchar4 rr = make_uchar4((u8)r0, (u8)r1, (u8)r2, (u8)r3);
    ((uchar4*)rank)[i] = rr;
}

__global__ __launch_bounds__(256) void scan_a(const int* __restrict__ cnt,
                                              int* __restrict__ partials) {
    __shared__ int ws[4];
    int b = blockIdx.x, tid = threadIdx.x, lane = tid & 63, wid = tid >> 6;
    int i0 = b * 1024 + tid * 4;
    int s = 0;
#pragma unroll
    for (int k = 0; k < 4; ++k) { int i = i0 + k; if (i < NK) s += cnt[i]; }
#pragma unroll
    for (int d = 32; d > 0; d >>= 1) s += __shfl_down(s, d);
    if (lane == 0) ws[wid] = s;
    __syncthreads();
    if (tid == 0) partials[b] = ws[0] + ws[1] + ws[2] + ws[3];
}

__global__ __launch_bounds__(512) void scan_b(int* __restrict__ partials) {
    __shared__ int s[512];
    int tid = threadIdx.x;
    int v = (tid < NBCHUNK) ? partials[tid] : 0;
    s[tid] = v;
    __syncthreads();
    for (int d = 1; d < 512; d <<= 1) {
        int u = (tid >= d) ? s[tid - d] : 0;
        __syncthreads();
        s[tid] += u;
        __syncthreads();
    }
    if (tid < NBCHUNK) partials[tid] = s[tid] - v;   // exclusive
}

__global__ __launch_bounds__(256) void scan_c(const int* __restrict__ cnt,
                                              const int* __restrict__ partials,
                                              int* __restrict__ offs) {
    __shared__ int wsum[4];
    int b = blockIdx.x, tid = threadIdx.x, lane = tid & 63, wid = tid >> 6;
    int i0 = b * 1024 + tid * 4;
    int c0 = (i0 + 0 < NK) ? cnt[i0 + 0] : 0;
    int c1 = (i0 + 1 < NK) ? cnt[i0 + 1] : 0;
    int c2 = (i0 + 2 < NK) ? cnt[i0 + 2] : 0;
    int c3 = (i0 + 3 < NK) ? cnt[i0 + 3] : 0;
    int lsum = c0 + c1 + c2 + c3;
    int v = lsum;
#pragma unroll
    for (int d = 1; d < 64; d <<= 1) {
        int u = __shfl_up(v, d);
        if (lane >= d) v += u;
    }
    int wexcl = v - lsum;
    if (lane == 63) wsum[wid] = v;
    __syncthreads();
    int bexcl = 0;
    for (int w = 0; w < wid; ++w) bexcl += wsum[w];
    int base = partials[b] + bexcl + wexcl;
    if (i0 + 0 < NK) offs[i0 + 0] = base; base += c0;
    if (i0 + 1 < NK) offs[i0 + 1] = base; base += c1;
    if (i0 + 2 < NK) offs[i0 + 2] = base; base += c2;
    if (i0 + 3 < NK) offs[i0 + 3] = base;
}

// ---------------------------------------------------------------------------
// Tier A place: NO atomics (pos = offs[key] + rank[i]); all stores
// independent -> full MLP. efb rows are full 64B-line nontemporal stores.
// ---------------------------------------------------------------------------
__global__ __launch_bounds__(256) void place_edges_a(const int* __restrict__ eidx,
                                                     const int* __restrict__ etype,
                                                     const u8* __restrict__ rank,
                                                     const int* __restrict__ offs,
                                                     const float* __restrict__ ef,
                                                     int* __restrict__ srcperm,
                                                     bf16* __restrict__ efb) {
    int i = blockIdx.x * 256 + threadIdx.x;
    if (i >= N_EDGES) return;
    int d = eidx[N_EDGES + i];
    int s = eidx[i];
    int t = etype[i];
    int pos = offs[4 * d + t] + (int)rank[i];
    const f32x4* src4 = (const f32x4*)(ef + (size_t)i * 32);
    __attribute__((aligned(16))) bf16 tmp[32];
#pragma unroll
    for (int k = 0; k < 8; ++k) {
        f32x4 f = src4[k];
        tmp[4 * k + 0] = __float2bfloat16(f.x);
        tmp[4 * k + 1] = __float2bfloat16(f.y);
        tmp[4 * k + 2] = __float2bfloat16(f.z);
        tmp[4 * k + 3] = __float2bfloat16(f.w);
    }
    f32x4* dst4 = (f32x4*)(efb + (size_t)pos * 32);
#pragma unroll
    for (int k = 0; k < 4; ++k)
        __builtin_nontemporal_store(((const f32x4*)tmp)[k], dst4 + k);
    __builtin_nontemporal_store(s, srcperm + pos);
}

// ---------------------------------------------------------------------------
// Tier A aggregate, two loops per node:
//  L1: xout gather (batched srcperm + readlane broadcast, 8-deep MLP)
//  L2: ef columns over the node's CONTIGUOUS efb slice, all 64 lanes
//      (lane = col + 32*half, 2 rows/iter, 128B coalesced), 3-way
//      predicated accumulate vs segment bounds, one shfl fold at end.
// ---------------------------------------------------------------------------
__global__ __launch_bounds__(256) void aggregate_stream(const int* __restrict__ srcperm,
                                                        const int* __restrict__ offs,
                                                        const bf16* __restrict__ xout,
                                                        const bf16* __restrict__ efb,
                                                        bf16* __restrict__ B) {
    int wid = threadIdx.x >> 6, lane = threadIdx.x & 63;
    int n = blockIdx.x * 4 + wid;
    if (n >= N_NODES) return;
    int4 o = ((const int4*)offs)[n];           // starts t0,t1,t2, end
    int beg = __builtin_amdgcn_readfirstlane(o.x);
    int y   = __builtin_amdgcn_readfirstlane(o.y);
    int z   = __builtin_amdgcn_readfirstlane(o.z);
    int end = __builtin_amdgcn_readfirstlane(o.w);
    float a0 = 0.f, a1 = 0.f, a2 = 0.f;

    // ---- L1: xout gathers ----
    for (int base = beg; base < end; base += 64) {
        int m = end - base; if (m > 64) m = 64;
        int sp = (lane < m) ? srcperm[base + lane] : 0;
        int j = 0;
        for (; j + 8 <= m; j += 8) {
            int s0 = __builtin_amdgcn_readlane(sp, j + 0);
            int s1 = __builtin_amdgcn_readlane(sp, j + 1);
            int s2 = __builtin_amdgcn_readlane(sp, j + 2);
            int s3 = __builtin_amdgcn_readlane(sp, j + 3);
            int s4 = __builtin_amdgcn_readlane(sp, j + 4);
            int s5 = __builtin_amdgcn_readlane(sp, j + 5);
            int s6 = __builtin_amdgcn_readlane(sp, j + 6);
            int s7 = __builtin_amdgcn_readlane(sp, j + 7);
            float x0 = __bfloat162float(xout[(size_t)s0 * 64 + lane]);
            float x1 = __bfloat162float(xout[(size_t)s1 * 64 + lane]);
            float x2 = __bfloat162float(xout[(size_t)s2 * 64 + lane]);
            float x3 = __bfloat162float(xout[(size_t)s3 * 64 + lane]);
            float x4 = __bfloat162float(xout[(size_t)s4 * 64 + lane]);
            float x5 = __bfloat162float(xout[(size_t)s5 * 64 + lane]);
            float x6 = __bfloat162float(xout[(size_t)s6 * 64 + lane]);
            float x7 = __bfloat162float(xout[(size_t)s7 * 64 + lane]);
#pragma unroll
            for (int k = 0; k < 8; ++k) {
                int idx = base + j + k;                     // scalar
                float xv = (k == 0) ? x0 : (k == 1) ? x1 : (k == 2) ? x2 : (k == 3) ? x3
                         : (k == 4) ? x4 : (k == 5) ? x5 : (k == 6) ? x6 : x7;
                if (idx < y)      a0 += xv;
                else if (idx < z) a1 += xv;
                else              a2 += xv;
            }
        }
        for (; j < m; ++j) {
            int s = __builtin_amdgcn_readlane(sp, j);
            float xv = __bfloat162float(xout[(size_t)s * 64 + lane]);
            int idx = base + j;
            if (idx < y)      a0 += xv;
            else if (idx < z) a1 += xv;
            else              a2 += xv;
        }
    }

    // ---- L2: ef columns, full wave ----
    float b0 = 0.f, b1 = 0.f, b2 = 0.f;
    {
        int c = lane & 31, h = lane >> 5;
        for (int r = beg + h; r < end; r += 2) {
            float v = __bfloat162float(efb[(size_t)r * 32 + c]);
            float v0 = (r < y)  ? v : 0.f;
            float v2 = (r >= z) ? v : 0.f;
            b0 += v0; b2 += v2; b1 += v - v0 - v2;
        }
        b0 += __shfl_down(b0, 32);
        b1 += __shfl_down(b1, 32);
        b2 += __shfl_down(b2, 32);
    }

    bf16* Bn = B + (size_t)n * KCAT;
    Bn[lane]       = __float2bfloat16(a0);
    Bn[64 + lane]  = __float2bfloat16(a1);
    Bn[128 + lane] = __float2bfloat16(a2);
    if (lane < 32) {
        Bn[192 + lane] = __float2bfloat16(b0);
        Bn[224 + lane] = __float2bfloat16(b1);
        Bn[256 + lane] = __float2bfloat16(b2);
    }
}

// ---------------------------------------------------------------------------
// Tier B (smaller ws): u64 payload, gathered fp32 ef, rank-based place.
// ---------------------------------------------------------------------------
__global__ __launch_bounds__(256) void place_edges_b(const int* __restrict__ eidx,
                                                     const int* __restrict__ etype,
                                                     const u8* __restrict__ rank,
                                                     const int* __restrict__ offs,
                                                     u64* __restrict__ pay) {
    int i = blockIdx.x * 256 + threadIdx.x;
    if (i < N_EDGES) {
        int d = eidx[N_EDGES + i];
        int s = eidx[i];
        int t = etype[i];
        int pos = offs[4 * d + t] + (int)rank[i];
        pay[pos] = (u64)(unsigned)s | ((u64)(unsigned)i << 32);
    }
}

__device__ __forceinline__ void agg_seg(const u64* __restrict__ pay, int lo, int hi,
                                        int lane,
                                        const bf16* __restrict__ xout,
                                        const float* __restrict__ ef,
                                        float& a, float& b) {
    for (int base = lo; base < hi; base += 64) {
        int m = hi - base; if (m > 64) m = 64;
        u64 p = (lane < m) ? pay[base + lane] : 0ull;
        int plo = (int)(unsigned)p;
        int phi = (int)(unsigned)(p >> 32);
        for (int j = 0; j < m; ++j) {
            int s = __builtin_amdgcn_readlane(plo, j);
            int e = __builtin_amdgcn_readlane(phi, j);
            float xv = __bfloat162float(xout[(size_t)s * 64 + lane]);
            float ev = (lane < 32) ? ef[(size_t)e * 32 + lane] : 0.f;
            a += xv; b += ev;
        }
    }
}

__global__ __launch_bounds__(256) void aggregate_b(const u64* __restrict__ pay,
                                                   const int* __restrict__ offs,
                                                   const bf16* __restrict__ xout,
                                                   const float* __restrict__ ef,
                                                   bf16* __restrict__ B) {
    int wid = threadIdx.x >> 6, lane = threadIdx.x & 63;
    int n = blockIdx.x * 4 + wid;
    if (n >= N_NODES) return;
    int4 o = ((const int4*)offs)[n];
    float a0 = 0.f, a1 = 0.f, a2 = 0.f, b0 = 0.f, b1 = 0.f, b2 = 0.f;
    agg_seg(pay, o.x, o.y, lane, xout, ef, a0, b0);
    agg_seg(pay, o.y, o.z, lane, xout, ef, a1, b1);
    agg_seg(pay, o.z, o.w, lane, xout, ef, a2, b2);
    bf16* Bn = B + (size_t)n * KCAT;
    Bn[lane]       = __float2bfloat16(a0);
    Bn[64 + lane]  = __float2bfloat16(a1);
    Bn[128 + lane] = __float2bfloat16(a2);
    if (lane < 32) {
        Bn[192 + lane] = __float2bfloat16(b0);
        Bn[224 + lane] = __float2bfloat16(b1);
        Bn[256 + lane] = __float2bfloat16(b2);
    }
}

// ---------------------------------------------------------------------------
// K3: out = B(bf16) @ Wcat(fp32), Wcat[288][64] remapped from W_msg on load.
// ---------------------------------------------------------------------------
__global__ __launch_bounds__(256) void final_gemm(const bf16* __restrict__ B,
                                                  const float* __restrict__ Wm,
                                                  float* __restrict__ out) {
    __shared__ float As[64][33];   // +1 pad
    __shared__ float Ws[32][64];
    int tid = threadIdx.x;
    int n0 = blockIdx.x * 64;
    int tx = tid & 15;
    int ty = tid >> 4;
    float acc[4][4] = {};

    for (int k0 = 0; k0 < KCAT; k0 += 32) {
#pragma unroll
        for (int i = 0; i < 8; ++i) {
            int f = i * 256 + tid;
            int r = f >> 5, cc = f & 31;
            int n = n0 + r;
            As[r][cc] = (n < N_NODES) ? __bfloat162float(B[(size_t)n * KCAT + k0 + cc]) : 0.f;
        }
#pragma unroll
        for (int i = 0; i < 8; ++i) {
            int f = i * 256 + tid;
            int kk = f >> 6, j = f & 63;
            int r = k0 + kk;
            int t, kin;
            if (r < 192) { t = r >> 6; kin = r & 63; }
            else         { int q = r - 192; t = q >> 5; kin = 64 + (q & 31); }
            Ws[kk][j] = Wm[(t * 96 + kin) * 64 + j];
        }
        __syncthreads();
#pragma unroll
        for (int kk = 0; kk < 32; ++kk) {
            float a0 = As[ty * 4 + 0][kk];
            float a1 = As[ty * 4 + 1][kk];
            float a2 = As[ty * 4 + 2][kk];
            float a3 = As[ty * 4 + 3][kk];
            float4 w = *(const float4*)&Ws[kk][tx * 4];
            acc[0][0] = fmaf(a0, w.x, acc[0][0]); acc[0][1] = fmaf(a0, w.y, acc[0][1]);
            acc[0][2] = fmaf(a0, w.z, acc[0][2]); acc[0][3] = fmaf(a0, w.w, acc[0][3]);
            acc[1][0] = fmaf(a1, w.x, acc[1][0]); acc[1][1] = fmaf(a1, w.y, acc[1][1]);
            acc[1][2] = fmaf(a1, w.z, acc[1][2]); acc[1][3] = fmaf(a1, w.w, acc[1][3]);
            acc[2][0] = fmaf(a2, w.x, acc[2][0]); acc[2][1] = fmaf(a2, w.y, acc[2][1]);
            acc[2][2] = fmaf(a2, w.z, acc[2][2]); acc[2][3] = fmaf(a2, w.w, acc[2][3]);
            acc[3][0] = fmaf(a3, w.x, acc[3][0]); acc[3][1] = fmaf(a3, w.y, acc[3][1]);
            acc[3][2] = fmaf(a3, w.z, acc[3][2]); acc[3][3] = fmaf(a3, w.w, acc[3][3]);
        }
        __syncthreads();
    }
#pragma unroll
    for (int r = 0; r < 4; ++r) {
        int n = n0 + ty * 4 + r;
        if (n < N_NODES) {
            float4 v = make_float4(acc[r][0], acc[r][1], acc[r][2], acc[r][3]);
            *(float4*)&out[(size_t)n * 64 + tx * 4] = v;
        }
    }
}

// ---------------------------------------------------------------------------
// Fallback (ws tiny): direct wave-per-edge, fp32.
// ---------------------------------------------------------------------------
__global__ __launch_bounds__(256) void fallback_edge(const float* __restrict__ nf,
                                                     const float* __restrict__ ef,
                                                     const float* __restrict__ Wn,
                                                     const float* __restrict__ Wm,
                                                     const int* __restrict__ ntype,
                                                     const int* __restrict__ etype,
                                                     const int* __restrict__ eidx,
                                                     float* __restrict__ out) {
    __shared__ float wn[2 * 64 * 64];
    __shared__ float wm[3 * 96 * 64];
    for (int i = threadIdx.x; i < 2 * 64 * 64; i += 256) wn[i] = Wn[i];
    for (int i = threadIdx.x; i < 3 * 96 * 64; i += 256) wm[i] = Wm[i];
    __syncthreads();
    int wid = threadIdx.x >> 6, lane = threadIdx.x & 63;
    for (int e = blockIdx.x * 4 + wid; e < N_EDGES; e += gridDim.x * 4) {
        int t = etype[e];
        int s = eidx[e];
        int d = eidx[N_EDGES + e];
        int nt = ntype[s];
        float xs = nf[(long)s * 64 + lane];
        const float* wcol = &wn[nt * 4096 + lane];
        float xo = 0.f;
#pragma unroll 16
        for (int k = 0; k < 64; ++k) xo = fmaf(__shfl(xs, k), wcol[k * 64], xo);
        float ev = ef[(long)e * 32 + (lane & 31)];
        const float* mcol = &wm[t * 96 * 64 + lane];
        float m = 0.f;
#pragma unroll 16
        for (int k = 0; k < 64; ++k) m = fmaf(__shfl(xo, k), mcol[k * 64], m);
#pragma unroll 8
        for (int k = 0; k < 32; ++k) m = fmaf(__shfl(ev, k), mcol[(64 + k) * 64], m);
        atomicAdd(&out[(long)d * 64 + lane], m);
    }
}

// ---------------------------------------------------------------------------
extern "C" void kernel_launch(void* const* d_in, const int* in_sizes, int n_in,
                              void* d_out, int out_size, void* d_ws, size_t ws_size,
                              hipStream_t stream) {
    const float* nf    = (const float*)d_in[0];
    const float* ef    = (const float*)d_in[1];
    const float* Wn    = (const float*)d_in[2];
    const float* Wm    = (const float*)d_in[3];
    const int*   ntype = (const int*)d_in[4];
    const int*   etype = (const int*)d_in[5];
    const int*   eidx  = (const int*)d_in[6];
    float* out = (float*)d_out;

    const size_t xout_bytes = (size_t)N_NODES * 64 * 2;        // 12.8 MB bf16
    const size_t b_bytes    = (size_t)N_NODES * KCAT * 2;      // 57.6 MB bf16
    const size_t efb_bytes  = (size_t)N_EDGES * 32 * 2;        // 102.4 MB bf16
    const size_t metaB_bytes = (size_t)(2 * NK + 512) * 4 + N_EDGES;

    if (ws_size >= xout_bytes + b_bytes + efb_bytes) {
        // ---- Tier A: streaming-ef, atomic-free place ----
        bf16* xout = (bf16*)d_ws;
        bf16* B    = (bf16*)((char*)d_ws + xout_bytes);
        bf16* efb  = (bf16*)((char*)d_ws + xout_bytes + b_bytes);
        // scratch in d_out (~11.3 MB < 25.6 MB); final_gemm fully overwrites
        // d_out at the end of every call.
        int* srcperm  = (int*)d_out;            // 6.4 MB
        int* cnt      = srcperm + N_EDGES;      // 1.6 MB
        int* offs     = cnt + NK;               // 1.6 MB
        int* partials = offs + NK;              // pad to 512 ints
        u8*  rank     = (u8*)(partials + 512);  // 1.6 MB

        zero_buf<<<400, 256, 0, stream>>>((float4*)cnt, (long)(NK / 4));
        node_xform<<<1563, 256, 0, stream>>>(nf, Wn, ntype, xout);
        count_rank<<<(N_EDGES / 4 + 255) / 256, 256, 0, stream>>>(eidx, etype, cnt, rank);
        scan_a<<<NBCHUNK, 256, 0, stream>>>(cnt, partials);
        scan_b<<<1, 512, 0, stream>>>(partials);
        scan_c<<<NBCHUNK, 256, 0, stream>>>(cnt, partials, offs);
        place_edges_a<<<(N_EDGES + 255) / 256, 256, 0, stream>>>(eidx, etype, rank, offs, ef, srcperm, efb);
        aggregate_stream<<<(N_NODES + 3) / 4, 256, 0, stream>>>(srcperm, offs, xout, efb, B);
        final_gemm<<<(N_NODES + 63) / 64, 256, 0, stream>>>(B, Wm, out);
    } else if (ws_size >= xout_bytes + b_bytes + metaB_bytes) {
        // ---- Tier B: gathered-ef path ----
        bf16* xout = (bf16*)d_ws;
        bf16* B    = (bf16*)((char*)d_ws + xout_bytes);
        int* cnt      = (int*)((char*)d_ws + xout_bytes + b_bytes);
        int* offs     = cnt + NK;
        int* partials = offs + NK;
        u8*  rank     = (u8*)(partials + 512);
        u64* pay = (u64*)d_out;   // 12.8 MB < 25.6 MB

        zero_buf<<<400, 256, 0, stream>>>((float4*)cnt, (long)(NK / 4));
        node_xform<<<1563, 256, 0, stream>>>(nf, Wn, ntype, xout);
        count_rank<<<(N_EDGES / 4 + 255) / 256, 256, 0, stream>>>(eidx, etype, cnt, rank);
        scan_a<<<NBCHUNK, 256, 0, stream>>>(cnt, partials);
        scan_b<<<1, 512, 0, stream>>>(partials);
        scan_c<<<NBCHUNK, 256, 0, stream>>>(cnt, partials, offs);
        place_edges_b<<<(N_EDGES + 255) / 256, 256, 0, stream>>>(eidx, etype, rank, offs, pay);
        aggregate_b<<<(N_NODES + 3) / 4, 256, 0, stream>>>(pay, offs, xout, ef, B);
        final_gemm<<<(N_NODES + 63) / 64, 256, 0, stream>>>(B, Wm, out);
    } else {
        zero_buf<<<2048, 256, 0, stream>>>((float4*)d_out, (long)((size_t)out_size * 4 / 16));
        fallback_edge<<<4096, 256, 0, stream>>>(nf, ef, Wn, Wm, ntype, etype, eidx, out);
    }
}

// Round 8
// 498.964 us; speedup vs baseline: 1.3519x; 1.3519x over previous
//
#include <hip/hip_runtime.h>
#include <hip/hip_bf16.h>

#define N_NODES 100000
#define N_EDGES 1600000
#define D_IN 64
#define D_OUT 64
#define E_DIM 32
#define KCAT 288            // 3*64 (S buckets) + 3*32 (T buckets)
#define NK (4 * N_NODES)    // sort keys: 4*dst + etype (slot 3 unused -> count 0)
#define NBCHUNK 391         // ceil(NK / 1024)

typedef unsigned long long u64;
typedef __hip_bfloat16 bf16;
typedef unsigned char u8;
typedef float __attribute__((ext_vector_type(4))) f32x4;

// ---------------------------------------------------------------------------
// zero helper (capture-safe)
// ---------------------------------------------------------------------------
__global__ __launch_bounds__(256) void zero_buf(float4* __restrict__ p, long n4) {
    long i = (long)blockIdx.x * 256 + threadIdx.x;
    long stride = (long)gridDim.x * 256;
    float4 z = make_float4(0.f, 0.f, 0.f, 0.f);
    for (; i < n4; i += stride) p[i] = z;
}

// ---------------------------------------------------------------------------
// K1: xout[n] = nf[n] @ W_node[ntype[n]]  (wave/node, grid-strided, bf16 out)
// ---------------------------------------------------------------------------
__global__ __launch_bounds__(256) void node_xform(const float* __restrict__ nf,
                                                  const float* __restrict__ Wn,
                                                  const int* __restrict__ ntype,
                                                  bf16* __restrict__ xout) {
    __shared__ float wl[2 * 64 * 64];   // 32 KB
    for (int i = threadIdx.x; i < 2 * 64 * 64; i += 256) wl[i] = Wn[i];
    __syncthreads();
    int wid = threadIdx.x >> 6, lane = threadIdx.x & 63;
    int gw = blockIdx.x * 4 + wid, nw = gridDim.x * 4;
    for (int n = gw; n < N_NODES; n += nw) {
        int t = ntype[n];                          // wave-uniform
        float x = nf[(size_t)n * 64 + lane];
        const float* wcol = &wl[t * 4096 + lane];
        float acc = 0.f;
#pragma unroll
        for (int k = 0; k < 64; ++k)
            acc = fmaf(__shfl(x, k), wcol[k * 64], acc);
        xout[(size_t)n * 64 + lane] = __float2bfloat16(acc);
    }
}

// ---------------------------------------------------------------------------
// count + rank: rank[i] = arrival order within key (4*dst+etype).
// Key multiplicity is Poisson(5.3) -> u8 cannot overflow (max ~40).
// ---------------------------------------------------------------------------
__global__ __launch_bounds__(256) void count_rank(const int* __restrict__ eidx,
                                                  const int* __restrict__ etype,
                                                  int* __restrict__ cnt,
                                                  u8* __restrict__ rank) {
    int i = blockIdx.x * 256 + threadIdx.x;   // edge quad id
    if (i >= N_EDGES / 4) return;
    int4 d = ((const int4*)(eidx + N_EDGES))[i];
    int4 t = ((const int4*)etype)[i];
    int r0 = atomicAdd(&cnt[4 * d.x + t.x], 1);
    int r1 = atomicAdd(&cnt[4 * d.y + t.y], 1);
    int r2 = atomicAdd(&cnt[4 * d.z + t.z], 1);
    int r3 = atomicAdd(&cnt[4 * d.w + t.w], 1);
    uchar4 rr = make_uchar4((u8)r0, (u8)r1, (u8)r2, (u8)r3);
    ((uchar4*)rank)[i] = rr;
}

__global__ __launch_bounds__(256) void scan_a(const int* __restrict__ cnt,
                                              int* __restrict__ partials) {
    __shared__ int ws[4];
    int b = blockIdx.x, tid = threadIdx.x, lane = tid & 63, wid = tid >> 6;
    int i0 = b * 1024 + tid * 4;
    int s = 0;
#pragma unroll
    for (int k = 0; k < 4; ++k) { int i = i0 + k; if (i < NK) s += cnt[i]; }
#pragma unroll
    for (int d = 32; d > 0; d >>= 1) s += __shfl_down(s, d);
    if (lane == 0) ws[wid] = s;
    __syncthreads();
    if (tid == 0) partials[b] = ws[0] + ws[1] + ws[2] + ws[3];
}

__global__ __launch_bounds__(512) void scan_b(int* __restrict__ partials) {
    __shared__ int s[512];
    int tid = threadIdx.x;
    int v = (tid < NBCHUNK) ? partials[tid] : 0;
    s[tid] = v;
    __syncthreads();
    for (int d = 1; d < 512; d <<= 1) {
        int u = (tid >= d) ? s[tid - d] : 0;
        __syncthreads();
        s[tid] += u;
        __syncthreads();
    }
    if (tid < NBCHUNK) partials[tid] = s[tid] - v;   // exclusive
}

__global__ __launch_bounds__(256) void scan_c(const int* __restrict__ cnt,
                                              const int* __restrict__ partials,
                                              int* __restrict__ offs) {
    __shared__ int wsum[4];
    int b = blockIdx.x, tid = threadIdx.x, lane = tid & 63, wid = tid >> 6;
    int i0 = b * 1024 + tid * 4;
    int c0 = (i0 + 0 < NK) ? cnt[i0 + 0] : 0;
    int c1 = (i0 + 1 < NK) ? cnt[i0 + 1] : 0;
    int c2 = (i0 + 2 < NK) ? cnt[i0 + 2] : 0;
    int c3 = (i0 + 3 < NK) ? cnt[i0 + 3] : 0;
    int lsum = c0 + c1 + c2 + c3;
    int v = lsum;
#pragma unroll
    for (int d = 1; d < 64; d <<= 1) {
        int u = __shfl_up(v, d);
        if (lane >= d) v += u;
    }
    int wexcl = v - lsum;
    if (lane == 63) wsum[wid] = v;
    __syncthreads();
    int bexcl = 0;
    for (int w = 0; w < wid; ++w) bexcl += wsum[w];
    int base = partials[b] + bexcl + wexcl;
    if (i0 + 0 < NK) offs[i0 + 0] = base; base += c0;
    if (i0 + 1 < NK) offs[i0 + 1] = base; base += c1;
    if (i0 + 2 < NK) offs[i0 + 2] = base; base += c2;
    if (i0 + 3 < NK) offs[i0 + 3] = base;
}

// ---------------------------------------------------------------------------
// Tier A place: NO atomics (pos = offs[key] + rank[i]); all stores
// independent. PLAIN stores (L2 write-back coalesces the scattered 64B rows;
// nontemporal was a 2.4x regression in round 7).
// ---------------------------------------------------------------------------
__global__ __launch_bounds__(256) void place_edges_a(const int* __restrict__ eidx,
                                                     const int* __restrict__ etype,
                                                     const u8* __restrict__ rank,
                                                     const int* __restrict__ offs,
                                                     const float* __restrict__ ef,
                                                     int* __restrict__ srcperm,
                                                     bf16* __restrict__ efb) {
    int i = blockIdx.x * 256 + threadIdx.x;
    if (i >= N_EDGES) return;
    int d = eidx[N_EDGES + i];
    int s = eidx[i];
    int t = etype[i];
    int pos = offs[4 * d + t] + (int)rank[i];
    const f32x4* src4 = (const f32x4*)(ef + (size_t)i * 32);
    __attribute__((aligned(16))) bf16 tmp[32];
#pragma unroll
    for (int k = 0; k < 8; ++k) {
        f32x4 f = src4[k];
        tmp[4 * k + 0] = __float2bfloat16(f.x);
        tmp[4 * k + 1] = __float2bfloat16(f.y);
        tmp[4 * k + 2] = __float2bfloat16(f.z);
        tmp[4 * k + 3] = __float2bfloat16(f.w);
    }
    f32x4* dst4 = (f32x4*)(efb + (size_t)pos * 32);
#pragma unroll
    for (int k = 0; k < 4; ++k) dst4[k] = ((const f32x4*)tmp)[k];
    srcperm[pos] = s;
}

// ---------------------------------------------------------------------------
// Tier A aggregate, two loops per node:
//  L1: xout gather (batched srcperm + readlane broadcast, 8-deep MLP)
//  L2: ef columns over the node's CONTIGUOUS efb slice, all 64 lanes.
// ---------------------------------------------------------------------------
__global__ __launch_bounds__(256) void aggregate_stream(const int* __restrict__ srcperm,
                                                        const int* __restrict__ offs,
                                                        const bf16* __restrict__ xout,
                                                        const bf16* __restrict__ efb,
                                                        bf16* __restrict__ B) {
    int wid = threadIdx.x >> 6, lane = threadIdx.x & 63;
    int n = blockIdx.x * 4 + wid;
    if (n >= N_NODES) return;
    int4 o = ((const int4*)offs)[n];           // starts t0,t1,t2, end
    int beg = __builtin_amdgcn_readfirstlane(o.x);
    int y   = __builtin_amdgcn_readfirstlane(o.y);
    int z   = __builtin_amdgcn_readfirstlane(o.z);
    int end = __builtin_amdgcn_readfirstlane(o.w);
    float a0 = 0.f, a1 = 0.f, a2 = 0.f;

    // ---- L1: xout gathers ----
    for (int base = beg; base < end; base += 64) {
        int m = end - base; if (m > 64) m = 64;
        int sp = (lane < m) ? srcperm[base + lane] : 0;
        int j = 0;
        for (; j + 8 <= m; j += 8) {
            int s0 = __builtin_amdgcn_readlane(sp, j + 0);
            int s1 = __builtin_amdgcn_readlane(sp, j + 1);
            int s2 = __builtin_amdgcn_readlane(sp, j + 2);
            int s3 = __builtin_amdgcn_readlane(sp, j + 3);
            int s4 = __builtin_amdgcn_readlane(sp, j + 4);
            int s5 = __builtin_amdgcn_readlane(sp, j + 5);
            int s6 = __builtin_amdgcn_readlane(sp, j + 6);
            int s7 = __builtin_amdgcn_readlane(sp, j + 7);
            float x0 = __bfloat162float(xout[(size_t)s0 * 64 + lane]);
            float x1 = __bfloat162float(xout[(size_t)s1 * 64 + lane]);
            float x2 = __bfloat162float(xout[(size_t)s2 * 64 + lane]);
            float x3 = __bfloat162float(xout[(size_t)s3 * 64 + lane]);
            float x4 = __bfloat162float(xout[(size_t)s4 * 64 + lane]);
            float x5 = __bfloat162float(xout[(size_t)s5 * 64 + lane]);
            float x6 = __bfloat162float(xout[(size_t)s6 * 64 + lane]);
            float x7 = __bfloat162float(xout[(size_t)s7 * 64 + lane]);
#pragma unroll
            for (int k = 0; k < 8; ++k) {
                int idx = base + j + k;                     // scalar
                float xv = (k == 0) ? x0 : (k == 1) ? x1 : (k == 2) ? x2 : (k == 3) ? x3
                         : (k == 4) ? x4 : (k == 5) ? x5 : (k == 6) ? x6 : x7;
                if (idx < y)      a0 += xv;
                else if (idx < z) a1 += xv;
                else              a2 += xv;
            }
        }
        for (; j < m; ++j) {
            int s = __builtin_amdgcn_readlane(sp, j);
            float xv = __bfloat162float(xout[(size_t)s * 64 + lane]);
            int idx = base + j;
            if (idx < y)      a0 += xv;
            else if (idx < z) a1 += xv;
            else              a2 += xv;
        }
    }

    // ---- L2: ef columns, full wave ----
    float b0 = 0.f, b1 = 0.f, b2 = 0.f;
    {
        int c = lane & 31, h = lane >> 5;
        for (int r = beg + h; r < end; r += 2) {
            float v = __bfloat162float(efb[(size_t)r * 32 + c]);
            float v0 = (r < y)  ? v : 0.f;
            float v2 = (r >= z) ? v : 0.f;
            b0 += v0; b2 += v2; b1 += v - v0 - v2;
        }
        b0 += __shfl_down(b0, 32);
        b1 += __shfl_down(b1, 32);
        b2 += __shfl_down(b2, 32);
    }

    bf16* Bn = B + (size_t)n * KCAT;
    Bn[lane]       = __float2bfloat16(a0);
    Bn[64 + lane]  = __float2bfloat16(a1);
    Bn[128 + lane] = __float2bfloat16(a2);
    if (lane < 32) {
        Bn[192 + lane] = __float2bfloat16(b0);
        Bn[224 + lane] = __float2bfloat16(b1);
        Bn[256 + lane] = __float2bfloat16(b2);
    }
}

// ---------------------------------------------------------------------------
// Tier B (smaller ws): u64 payload, gathered fp32 ef, rank-based place.
// ---------------------------------------------------------------------------
__global__ __launch_bounds__(256) void place_edges_b(const int* __restrict__ eidx,
                                                     const int* __restrict__ etype,
                                                     const u8* __restrict__ rank,
                                                     const int* __restrict__ offs,
                                                     u64* __restrict__ pay) {
    int i = blockIdx.x * 256 + threadIdx.x;
    if (i < N_EDGES) {
        int d = eidx[N_EDGES + i];
        int s = eidx[i];
        int t = etype[i];
        int pos = offs[4 * d + t] + (int)rank[i];
        pay[pos] = (u64)(unsigned)s | ((u64)(unsigned)i << 32);
    }
}

__device__ __forceinline__ void agg_seg(const u64* __restrict__ pay, int lo, int hi,
                                        int lane,
                                        const bf16* __restrict__ xout,
                                        const float* __restrict__ ef,
                                        float& a, float& b) {
    for (int base = lo; base < hi; base += 64) {
        int m = hi - base; if (m > 64) m = 64;
        u64 p = (lane < m) ? pay[base + lane] : 0ull;
        int plo = (int)(unsigned)p;
        int phi = (int)(unsigned)(p >> 32);
        for (int j = 0; j < m; ++j) {
            int s = __builtin_amdgcn_readlane(plo, j);
            int e = __builtin_amdgcn_readlane(phi, j);
            float xv = __bfloat162float(xout[(size_t)s * 64 + lane]);
            float ev = (lane < 32) ? ef[(size_t)e * 32 + lane] : 0.f;
            a += xv; b += ev;
        }
    }
}

__global__ __launch_bounds__(256) void aggregate_b(const u64* __restrict__ pay,
                                                   const int* __restrict__ offs,
                                                   const bf16* __restrict__ xout,
                                                   const float* __restrict__ ef,
                                                   bf16* __restrict__ B) {
    int wid = threadIdx.x >> 6, lane = threadIdx.x & 63;
    int n = blockIdx.x * 4 + wid;
    if (n >= N_NODES) return;
    int4 o = ((const int4*)offs)[n];
    float a0 = 0.f, a1 = 0.f, a2 = 0.f, b0 = 0.f, b1 = 0.f, b2 = 0.f;
    agg_seg(pay, o.x, o.y, lane, xout, ef, a0, b0);
    agg_seg(pay, o.y, o.z, lane, xout, ef, a1, b1);
    agg_seg(pay, o.z, o.w, lane, xout, ef, a2, b2);
    bf16* Bn = B + (size_t)n * KCAT;
    Bn[lane]       = __float2bfloat16(a0);
    Bn[64 + lane]  = __float2bfloat16(a1);
    Bn[128 + lane] = __float2bfloat16(a2);
    if (lane < 32) {
        Bn[192 + lane] = __float2bfloat16(b0);
        Bn[224 + lane] = __float2bfloat16(b1);
        Bn[256 + lane] = __float2bfloat16(b2);
    }
}

// ---------------------------------------------------------------------------
// K3: out = B(bf16) @ Wcat(fp32), Wcat[288][64] remapped from W_msg on load.
// ---------------------------------------------------------------------------
__global__ __launch_bounds__(256) void final_gemm(const bf16* __restrict__ B,
                                                  const float* __restrict__ Wm,
                                                  float* __restrict__ out) {
    __shared__ float As[64][33];   // +1 pad
    __shared__ float Ws[32][64];
    int tid = threadIdx.x;
    int n0 = blockIdx.x * 64;
    int tx = tid & 15;
    int ty = tid >> 4;
    float acc[4][4] = {};

    for (int k0 = 0; k0 < KCAT; k0 += 32) {
#pragma unroll
        for (int i = 0; i < 8; ++i) {
            int f = i * 256 + tid;
            int r = f >> 5, cc = f & 31;
            int n = n0 + r;
            As[r][cc] = (n < N_NODES) ? __bfloat162float(B[(size_t)n * KCAT + k0 + cc]) : 0.f;
        }
#pragma unroll
        for (int i = 0; i < 8; ++i) {
            int f = i * 256 + tid;
            int kk = f >> 6, j = f & 63;
            int r = k0 + kk;
            int t, kin;
            if (r < 192) { t = r >> 6; kin = r & 63; }
            else         { int q = r - 192; t = q >> 5; kin = 64 + (q & 31); }
            Ws[kk][j] = Wm[(t * 96 + kin) * 64 + j];
        }
        __syncthreads();
#pragma unroll
        for (int kk = 0; kk < 32; ++kk) {
            float a0 = As[ty * 4 + 0][kk];
            float a1 = As[ty * 4 + 1][kk];
            float a2 = As[ty * 4 + 2][kk];
            float a3 = As[ty * 4 + 3][kk];
            float4 w = *(const float4*)&Ws[kk][tx * 4];
            acc[0][0] = fmaf(a0, w.x, acc[0][0]); acc[0][1] = fmaf(a0, w.y, acc[0][1]);
            acc[0][2] = fmaf(a0, w.z, acc[0][2]); acc[0][3] = fmaf(a0, w.w, acc[0][3]);
            acc[1][0] = fmaf(a1, w.x, acc[1][0]); acc[1][1] = fmaf(a1, w.y, acc[1][1]);
            acc[1][2] = fmaf(a1, w.z, acc[1][2]); acc[1][3] = fmaf(a1, w.w, acc[1][3]);
            acc[2][0] = fmaf(a2, w.x, acc[2][0]); acc[2][1] = fmaf(a2, w.y, acc[2][1]);
            acc[2][2] = fmaf(a2, w.z, acc[2][2]); acc[2][3] = fmaf(a2, w.w, acc[2][3]);
            acc[3][0] = fmaf(a3, w.x, acc[3][0]); acc[3][1] = fmaf(a3, w.y, acc[3][1]);
            acc[3][2] = fmaf(a3, w.z, acc[3][2]); acc[3][3] = fmaf(a3, w.w, acc[3][3]);
        }
        __syncthreads();
    }
#pragma unroll
    for (int r = 0; r < 4; ++r) {
        int n = n0 + ty * 4 + r;
        if (n < N_NODES) {
            float4 v = make_float4(acc[r][0], acc[r][1], acc[r][2], acc[r][3]);
            *(float4*)&out[(size_t)n * 64 + tx * 4] = v;
        }
    }
}

// ---------------------------------------------------------------------------
// Fallback (ws tiny): direct wave-per-edge, fp32.
// ---------------------------------------------------------------------------
__global__ __launch_bounds__(256) void fallback_edge(const float* __restrict__ nf,
                                                     const float* __restrict__ ef,
                                                     const float* __restrict__ Wn,
                                                     const float* __restrict__ Wm,
                                                     const int* __restrict__ ntype,
                                                     const int* __restrict__ etype,
                                                     const int* __restrict__ eidx,
                                                     float* __restrict__ out) {
    __shared__ float wn[2 * 64 * 64];
    __shared__ float wm[3 * 96 * 64];
    for (int i = threadIdx.x; i < 2 * 64 * 64; i += 256) wn[i] = Wn[i];
    for (int i = threadIdx.x; i < 3 * 96 * 64; i += 256) wm[i] = Wm[i];
    __syncthreads();
    int wid = threadIdx.x >> 6, lane = threadIdx.x & 63;
    for (int e = blockIdx.x * 4 + wid; e < N_EDGES; e += gridDim.x * 4) {
        int t = etype[e];
        int s = eidx[e];
        int d = eidx[N_EDGES + e];
        int nt = ntype[s];
        float xs = nf[(long)s * 64 + lane];
        const float* wcol = &wn[nt * 4096 + lane];
        float xo = 0.f;
#pragma unroll 16
        for (int k = 0; k < 64; ++k) xo = fmaf(__shfl(xs, k), wcol[k * 64], xo);
        float ev = ef[(long)e * 32 + (lane & 31)];
        const float* mcol = &wm[t * 96 * 64 + lane];
        float m = 0.f;
#pragma unroll 16
        for (int k = 0; k < 64; ++k) m = fmaf(__shfl(xo, k), mcol[k * 64], m);
#pragma unroll 8
        for (int k = 0; k < 32; ++k) m = fmaf(__shfl(ev, k), mcol[(64 + k) * 64], m);
        atomicAdd(&out[(long)d * 64 + lane], m);
    }
}

// ---------------------------------------------------------------------------
extern "C" void kernel_launch(void* const* d_in, const int* in_sizes, int n_in,
                              void* d_out, int out_size, void* d_ws, size_t ws_size,
                              hipStream_t stream) {
    const float* nf    = (const float*)d_in[0];
    const float* ef    = (const float*)d_in[1];
    const float* Wn    = (const float*)d_in[2];
    const float* Wm    = (const float*)d_in[3];
    const int*   ntype = (const int*)d_in[4];
    const int*   etype = (const int*)d_in[5];
    const int*   eidx  = (const int*)d_in[6];
    float* out = (float*)d_out;

    const size_t xout_bytes = (size_t)N_NODES * 64 * 2;        // 12.8 MB bf16
    const size_t b_bytes    = (size_t)N_NODES * KCAT * 2;      // 57.6 MB bf16
    const size_t efb_bytes  = (size_t)N_EDGES * 32 * 2;        // 102.4 MB bf16
    const size_t metaB_bytes = (size_t)(2 * NK + 512) * 4 + N_EDGES;

    if (ws_size >= xout_bytes + b_bytes + efb_bytes) {
        // ---- Tier A: streaming-ef, atomic-free place ----
        bf16* xout = (bf16*)d_ws;
        bf16* B    = (bf16*)((char*)d_ws + xout_bytes);
        bf16* efb  = (bf16*)((char*)d_ws + xout_bytes + b_bytes);
        // scratch in d_out (~11.3 MB < 25.6 MB); final_gemm fully overwrites
        // d_out at the end of every call.
        int* srcperm  = (int*)d_out;            // 6.4 MB
        int* cnt      = srcperm + N_EDGES;      // 1.6 MB
        int* offs     = cnt + NK;               // 1.6 MB
        int* partials = offs + NK;              // pad to 512 ints
        u8*  rank     = (u8*)(partials + 512);  // 1.6 MB

        zero_buf<<<400, 256, 0, stream>>>((float4*)cnt, (long)(NK / 4));
        node_xform<<<1563, 256, 0, stream>>>(nf, Wn, ntype, xout);
        count_rank<<<(N_EDGES / 4 + 255) / 256, 256, 0, stream>>>(eidx, etype, cnt, rank);
        scan_a<<<NBCHUNK, 256, 0, stream>>>(cnt, partials);
        scan_b<<<1, 512, 0, stream>>>(partials);
        scan_c<<<NBCHUNK, 256, 0, stream>>>(cnt, partials, offs);
        place_edges_a<<<(N_EDGES + 255) / 256, 256, 0, stream>>>(eidx, etype, rank, offs, ef, srcperm, efb);
        aggregate_stream<<<(N_NODES + 3) / 4, 256, 0, stream>>>(srcperm, offs, xout, efb, B);
        final_gemm<<<(N_NODES + 63) / 64, 256, 0, stream>>>(B, Wm, out);
    } else if (ws_size >= xout_bytes + b_bytes + metaB_bytes) {
        // ---- Tier B: gathered-ef path ----
        bf16* xout = (bf16*)d_ws;
        bf16* B    = (bf16*)((char*)d_ws + xout_bytes);
        int* cnt      = (int*)((char*)d_ws + xout_bytes + b_bytes);
        int* offs     = cnt + NK;
        int* partials = offs + NK;
        u8*  rank     = (u8*)(partials + 512);
        u64* pay = (u64*)d_out;   // 12.8 MB < 25.6 MB

        zero_buf<<<400, 256, 0, stream>>>((float4*)cnt, (long)(NK / 4));
        node_xform<<<1563, 256, 0, stream>>>(nf, Wn, ntype, xout);
        count_rank<<<(N_EDGES / 4 + 255) / 256, 256, 0, stream>>>(eidx, etype, cnt, rank);
        scan_a<<<NBCHUNK, 256, 0, stream>>>(cnt, partials);
        scan_b<<<1, 512, 0, stream>>>(partials);
        scan_c<<<NBCHUNK, 256, 0, stream>>>(cnt, partials, offs);
        place_edges_b<<<(N_EDGES + 255) / 256, 256, 0, stream>>>(eidx, etype, rank, offs, pay);
        aggregate_b<<<(N_NODES + 3) / 4, 256, 0, stream>>>(pay, offs, xout, ef, B);
        final_gemm<<<(N_NODES + 63) / 64, 256, 0, stream>>>(B, Wm, out);
    } else {
        zero_buf<<<2048, 256, 0, stream>>>((float4*)d_out, (long)((size_t)out_size * 4 / 16));
        fallback_edge<<<4096, 256, 0, stream>>>(nf, ef, Wn, Wm, ntype, etype, eidx, out);
    }
}

// Round 9
// 361.180 us; speedup vs baseline: 1.8676x; 1.3815x over previous
//
#include <hip/hip_runtime.h>
#include <hip/hip_bf16.h>

#define N_NODES 100000
#define N_EDGES 1600000
#define D_IN 64
#define D_OUT 64
#define E_DIM 32
#define KCAT 288            // 3*64 (S buckets) + 3*32 (T buckets)
#define NK (4 * N_NODES)    // sort keys: 4*dst + etype (slot 3 unused -> count 0)
#define NBCHUNK 391         // ceil(NK / 1024)
#define XF_BLOCKS 1563      // node_xform side of fused_pre
#define CR_BLOCKS 1563      // count_rank side (400000 quads / 256)

typedef unsigned long long u64;
typedef __hip_bfloat16 bf16;
typedef unsigned char u8;

// ---------------------------------------------------------------------------
// zero helper (capture-safe)
// ---------------------------------------------------------------------------
__global__ __launch_bounds__(256) void zero_buf(float4* __restrict__ p, long n4) {
    long i = (long)blockIdx.x * 256 + threadIdx.x;
    long stride = (long)gridDim.x * 256;
    float4 z = make_float4(0.f, 0.f, 0.f, 0.f);
    for (; i < n4; i += stride) p[i] = z;
}

// ---------------------------------------------------------------------------
// fused_pre: blocks [0,XF_BLOCKS) do node_xform; the rest do count+rank.
// Overlaps VALU-bound transform with latency/atomic-bound counting.
// ---------------------------------------------------------------------------
__global__ __launch_bounds__(256) void fused_pre(const float* __restrict__ nf,
                                                 const float* __restrict__ Wn,
                                                 const int* __restrict__ ntype,
                                                 bf16* __restrict__ xout,
                                                 const int* __restrict__ eidx,
                                                 const int* __restrict__ etype,
                                                 int* __restrict__ cnt,
                                                 u8* __restrict__ rank) {
    __shared__ float wl[2 * 64 * 64];   // 32 KB (only used by xform side)
    if (blockIdx.x < XF_BLOCKS) {
        for (int i = threadIdx.x; i < 2 * 64 * 64; i += 256) wl[i] = Wn[i];
        __syncthreads();
        int wid = threadIdx.x >> 6, lane = threadIdx.x & 63;
        int gw = blockIdx.x * 4 + wid, nw = XF_BLOCKS * 4;
        for (int n = gw; n < N_NODES; n += nw) {
            int t = ntype[n];                          // wave-uniform
            float x = nf[(size_t)n * 64 + lane];
            const float* wcol = &wl[t * 4096 + lane];
            float acc = 0.f;
#pragma unroll
            for (int k = 0; k < 64; ++k)
                acc = fmaf(__shfl(x, k), wcol[k * 64], acc);
            xout[(size_t)n * 64 + lane] = __float2bfloat16(acc);
        }
    } else {
        int i = (blockIdx.x - XF_BLOCKS) * 256 + threadIdx.x;   // edge quad id
        if (i >= N_EDGES / 4) return;
        int4 d = ((const int4*)(eidx + N_EDGES))[i];
        int4 t = ((const int4*)etype)[i];
        int r0 = atomicAdd(&cnt[4 * d.x + t.x], 1);
        int r1 = atomicAdd(&cnt[4 * d.y + t.y], 1);
        int r2 = atomicAdd(&cnt[4 * d.z + t.z], 1);
        int r3 = atomicAdd(&cnt[4 * d.w + t.w], 1);
        ((uchar4*)rank)[i] = make_uchar4((u8)r0, (u8)r1, (u8)r2, (u8)r3);
    }
}

__global__ __launch_bounds__(256) void scan_a(const int* __restrict__ cnt,
                                              int* __restrict__ partials) {
    __shared__ int ws[4];
    int b = blockIdx.x, tid = threadIdx.x, lane = tid & 63, wid = tid >> 6;
    int i0 = b * 1024 + tid * 4;
    int s = 0;
#pragma unroll
    for (int k = 0; k < 4; ++k) { int i = i0 + k; if (i < NK) s += cnt[i]; }
#pragma unroll
    for (int d = 32; d > 0; d >>= 1) s += __shfl_down(s, d);
    if (lane == 0) ws[wid] = s;
    __syncthreads();
    if (tid == 0) partials[b] = ws[0] + ws[1] + ws[2] + ws[3];
}

__global__ __launch_bounds__(512) void scan_b(int* __restrict__ partials) {
    __shared__ int s[512];
    int tid = threadIdx.x;
    int v = (tid < NBCHUNK) ? partials[tid] : 0;
    s[tid] = v;
    __syncthreads();
    for (int d = 1; d < 512; d <<= 1) {
        int u = (tid >= d) ? s[tid - d] : 0;
        __syncthreads();
        s[tid] += u;
        __syncthreads();
    }
    if (tid < NBCHUNK) partials[tid] = s[tid] - v;   // exclusive
}

__global__ __launch_bounds__(256) void scan_c(const int* __restrict__ cnt,
                                              const int* __restrict__ partials,
                                              int* __restrict__ offs) {
    __shared__ int wsum[4];
    int b = blockIdx.x, tid = threadIdx.x, lane = tid & 63, wid = tid >> 6;
    int i0 = b * 1024 + tid * 4;
    int c0 = (i0 + 0 < NK) ? cnt[i0 + 0] : 0;
    int c1 = (i0 + 1 < NK) ? cnt[i0 + 1] : 0;
    int c2 = (i0 + 2 < NK) ? cnt[i0 + 2] : 0;
    int c3 = (i0 + 3 < NK) ? cnt[i0 + 3] : 0;
    int lsum = c0 + c1 + c2 + c3;
    int v = lsum;
#pragma unroll
    for (int d = 1; d < 64; d <<= 1) {
        int u = __shfl_up(v, d);
        if (lane >= d) v += u;
    }
    int wexcl = v - lsum;
    if (lane == 63) wsum[wid] = v;
    __syncthreads();
    int bexcl = 0;
    for (int w = 0; w < wid; ++w) bexcl += wsum[w];
    int base = partials[b] + bexcl + wexcl;
    if (i0 + 0 < NK) offs[i0 + 0] = base; base += c0;
    if (i0 + 1 < NK) offs[i0 + 1] = base; base += c1;
    if (i0 + 2 < NK) offs[i0 + 2] = base; base += c2;
    if (i0 + 3 < NK) offs[i0 + 3] = base;
}

// ---------------------------------------------------------------------------
// place_pay: ONLY an 8B payload scatter (pos = offs[key]+rank, no atomics).
// No ef permute -- aggregate gathers ef rows directly (full 128B lines).
// ---------------------------------------------------------------------------
__global__ __launch_bounds__(256) void place_pay(const int* __restrict__ eidx,
                                                 const int* __restrict__ etype,
                                                 const u8* __restrict__ rank,
                                                 const int* __restrict__ offs,
                                                 u64* __restrict__ pay) {
    int i = blockIdx.x * 256 + threadIdx.x;
    if (i >= N_EDGES) return;
    int d = eidx[N_EDGES + i];
    int s = eidx[i];
    int t = etype[i];
    int pos = offs[4 * d + t] + (int)rank[i];
    pay[pos] = (u64)(unsigned)s | ((u64)(unsigned)i << 32);
}

// ---------------------------------------------------------------------------
// aggregate_g: wave/node; per 8 edges issue 8 xout row-gathers (bf16, L3-
// resident) + 4 full-wave ef gathers (fp32 rows, 2 rows per wave-load:
// half = lane>>5 selects edge, col = lane&31). All 12 loads independent.
// Guarded accumulate (no tail loop). Zero atomics.
// ---------------------------------------------------------------------------
__global__ __launch_bounds__(256) void aggregate_g(const u64* __restrict__ pay,
                                                   const int* __restrict__ offs,
                                                   const bf16* __restrict__ xout,
                                                   const float* __restrict__ ef,
                                                   bf16* __restrict__ B) {
    int wid = threadIdx.x >> 6, lane = threadIdx.x & 63;
    int n = blockIdx.x * 4 + wid;
    if (n >= N_NODES) return;
    int4 o = ((const int4*)offs)[n];           // starts t0,t1,t2, end
    int beg = __builtin_amdgcn_readfirstlane(o.x);
    int y   = __builtin_amdgcn_readfirstlane(o.y);
    int z   = __builtin_amdgcn_readfirstlane(o.z);
    int end = __builtin_amdgcn_readfirstlane(o.w);
    float a0 = 0.f, a1 = 0.f, a2 = 0.f, b0 = 0.f, b1 = 0.f, b2 = 0.f;
    int col = lane & 31, half = lane >> 5;

    for (int base = beg; base < end; base += 64) {
        int m = end - base; if (m > 64) m = 64;
        u64 p = (lane < m) ? pay[base + lane] : 0ull;
        int plo = (int)(unsigned)p;            // src
        int phi = (int)(unsigned)(p >> 32);    // edge id
        for (int j = 0; j < m; j += 8) {
            // 8 scalar src + edge ids
            int s0 = __builtin_amdgcn_readlane(plo, j + 0);
            int s1 = __builtin_amdgcn_readlane(plo, j + 1);
            int s2 = __builtin_amdgcn_readlane(plo, j + 2);
            int s3 = __builtin_amdgcn_readlane(plo, j + 3);
            int s4 = __builtin_amdgcn_readlane(plo, j + 4);
            int s5 = __builtin_amdgcn_readlane(plo, j + 5);
            int s6 = __builtin_amdgcn_readlane(plo, j + 6);
            int s7 = __builtin_amdgcn_readlane(plo, j + 7);
            int e0 = __builtin_amdgcn_readlane(phi, j + 0);
            int e1 = __builtin_amdgcn_readlane(phi, j + 1);
            int e2 = __builtin_amdgcn_readlane(phi, j + 2);
            int e3 = __builtin_amdgcn_readlane(phi, j + 3);
            int e4 = __builtin_amdgcn_readlane(phi, j + 4);
            int e5 = __builtin_amdgcn_readlane(phi, j + 5);
            int e6 = __builtin_amdgcn_readlane(phi, j + 6);
            int e7 = __builtin_amdgcn_readlane(phi, j + 7);
            // 8 xout row-gathers (scalar base + lane -> saddr loads)
            float x0 = __bfloat162float(xout[(size_t)s0 * 64 + lane]);
            float x1 = __bfloat162float(xout[(size_t)s1 * 64 + lane]);
            float x2 = __bfloat162float(xout[(size_t)s2 * 64 + lane]);
            float x3 = __bfloat162float(xout[(size_t)s3 * 64 + lane]);
            float x4 = __bfloat162float(xout[(size_t)s4 * 64 + lane]);
            float x5 = __bfloat162float(xout[(size_t)s5 * 64 + lane]);
            float x6 = __bfloat162float(xout[(size_t)s6 * 64 + lane]);
            float x7 = __bfloat162float(xout[(size_t)s7 * 64 + lane]);
            // 4 full-wave ef gathers: each covers edge pair (2q, 2q+1)
            int r0_ = half ? e1 : e0;
            int r1_ = half ? e3 : e2;
            int r2_ = half ? e5 : e4;
            int r3_ = half ? e7 : e6;
            float v0 = ef[(size_t)r0_ * 32 + col];
            float v1 = ef[(size_t)r1_ * 32 + col];
            float v2 = ef[(size_t)r2_ * 32 + col];
            float v3 = ef[(size_t)r3_ * 32 + col];
            // xout accumulate: idx scalar -> uniform branches
#pragma unroll
            for (int k = 0; k < 8; ++k) {
                int idx = base + j + k;
                float xv = (k == 0) ? x0 : (k == 1) ? x1 : (k == 2) ? x2 : (k == 3) ? x3
                         : (k == 4) ? x4 : (k == 5) ? x5 : (k == 6) ? x6 : x7;
                if (idx < y)        a0 += xv;
                else if (idx < z)   a1 += xv;
                else if (idx < end) a2 += xv;
            }
            // ef accumulate: idx per-lane (half), predicated
#pragma unroll
            for (int q = 0; q < 4; ++q) {
                float vv = (q == 0) ? v0 : (q == 1) ? v1 : (q == 2) ? v2 : v3;
                int idx = base + j + 2 * q + half;
                vv = (idx < end) ? vv : 0.f;
                float c0_ = (idx < y)  ? vv : 0.f;
                float c2_ = (idx >= z) ? vv : 0.f;
                b0 += c0_; b2 += c2_; b1 += vv - c0_ - c2_;
            }
        }
    }
    // fold ef halves
    b0 += __shfl_down(b0, 32);
    b1 += __shfl_down(b1, 32);
    b2 += __shfl_down(b2, 32);

    bf16* Bn = B + (size_t)n * KCAT;
    Bn[lane]       = __float2bfloat16(a0);
    Bn[64 + lane]  = __float2bfloat16(a1);
    Bn[128 + lane] = __float2bfloat16(a2);
    if (lane < 32) {
        Bn[192 + lane] = __float2bfloat16(b0);
        Bn[224 + lane] = __float2bfloat16(b1);
        Bn[256 + lane] = __float2bfloat16(b2);
    }
}

// ---------------------------------------------------------------------------
// K3: out = B(bf16) @ Wcat(fp32), Wcat[288][64] remapped from W_msg on load.
// ---------------------------------------------------------------------------
__global__ __launch_bounds__(256) void final_gemm(const bf16* __restrict__ B,
                                                  const float* __restrict__ Wm,
                                                  float* __restrict__ out) {
    __shared__ float As[64][33];   // +1 pad
    __shared__ float Ws[32][64];
    int tid = threadIdx.x;
    int n0 = blockIdx.x * 64;
    int tx = tid & 15;
    int ty = tid >> 4;
    float acc[4][4] = {};

    for (int k0 = 0; k0 < KCAT; k0 += 32) {
#pragma unroll
        for (int i = 0; i < 8; ++i) {
            int f = i * 256 + tid;
            int r = f >> 5, cc = f & 31;
            int n = n0 + r;
            As[r][cc] = (n < N_NODES) ? __bfloat162float(B[(size_t)n * KCAT + k0 + cc]) : 0.f;
        }
#pragma unroll
        for (int i = 0; i < 8; ++i) {
            int f = i * 256 + tid;
            int kk = f >> 6, j = f & 63;
            int r = k0 + kk;
            int t, kin;
            if (r < 192) { t = r >> 6; kin = r & 63; }
            else         { int q = r - 192; t = q >> 5; kin = 64 + (q & 31); }
            Ws[kk][j] = Wm[(t * 96 + kin) * 64 + j];
        }
        __syncthreads();
#pragma unroll
        for (int kk = 0; kk < 32; ++kk) {
            float a0 = As[ty * 4 + 0][kk];
            float a1 = As[ty * 4 + 1][kk];
            float a2 = As[ty * 4 + 2][kk];
            float a3 = As[ty * 4 + 3][kk];
            float4 w = *(const float4*)&Ws[kk][tx * 4];
            acc[0][0] = fmaf(a0, w.x, acc[0][0]); acc[0][1] = fmaf(a0, w.y, acc[0][1]);
            acc[0][2] = fmaf(a0, w.z, acc[0][2]); acc[0][3] = fmaf(a0, w.w, acc[0][3]);
            acc[1][0] = fmaf(a1, w.x, acc[1][0]); acc[1][1] = fmaf(a1, w.y, acc[1][1]);
            acc[1][2] = fmaf(a1, w.z, acc[1][2]); acc[1][3] = fmaf(a1, w.w, acc[1][3]);
            acc[2][0] = fmaf(a2, w.x, acc[2][0]); acc[2][1] = fmaf(a2, w.y, acc[2][1]);
            acc[2][2] = fmaf(a2, w.z, acc[2][2]); acc[2][3] = fmaf(a2, w.w, acc[2][3]);
            acc[3][0] = fmaf(a3, w.x, acc[3][0]); acc[3][1] = fmaf(a3, w.y, acc[3][1]);
            acc[3][2] = fmaf(a3, w.z, acc[3][2]); acc[3][3] = fmaf(a3, w.w, acc[3][3]);
        }
        __syncthreads();
    }
#pragma unroll
    for (int r = 0; r < 4; ++r) {
        int n = n0 + ty * 4 + r;
        if (n < N_NODES) {
            float4 v = make_float4(acc[r][0], acc[r][1], acc[r][2], acc[r][3]);
            *(float4*)&out[(size_t)n * 64 + tx * 4] = v;
        }
    }
}

// ---------------------------------------------------------------------------
// Fallback (ws tiny): direct wave-per-edge, fp32.
// ---------------------------------------------------------------------------
__global__ __launch_bounds__(256) void fallback_edge(const float* __restrict__ nf,
                                                     const float* __restrict__ ef,
                                                     const float* __restrict__ Wn,
                                                     const float* __restrict__ Wm,
                                                     const int* __restrict__ ntype,
                                                     const int* __restrict__ etype,
                                                     const int* __restrict__ eidx,
                                                     float* __restrict__ out) {
    __shared__ float wn[2 * 64 * 64];
    __shared__ float wm[3 * 96 * 64];
    for (int i = threadIdx.x; i < 2 * 64 * 64; i += 256) wn[i] = Wn[i];
    for (int i = threadIdx.x; i < 3 * 96 * 64; i += 256) wm[i] = Wm[i];
    __syncthreads();
    int wid = threadIdx.x >> 6, lane = threadIdx.x & 63;
    for (int e = blockIdx.x * 4 + wid; e < N_EDGES; e += gridDim.x * 4) {
        int t = etype[e];
        int s = eidx[e];
        int d = eidx[N_EDGES + e];
        int nt = ntype[s];
        float xs = nf[(long)s * 64 + lane];
        const float* wcol = &wn[nt * 4096 + lane];
        float xo = 0.f;
#pragma unroll 16
        for (int k = 0; k < 64; ++k) xo = fmaf(__shfl(xs, k), wcol[k * 64], xo);
        float ev = ef[(long)e * 32 + (lane & 31)];
        const float* mcol = &wm[t * 96 * 64 + lane];
        float m = 0.f;
#pragma unroll 16
        for (int k = 0; k < 64; ++k) m = fmaf(__shfl(xo, k), mcol[k * 64], m);
#pragma unroll 8
        for (int k = 0; k < 32; ++k) m = fmaf(__shfl(ev, k), mcol[(64 + k) * 64], m);
        atomicAdd(&out[(long)d * 64 + lane], m);
    }
}

// ---------------------------------------------------------------------------
extern "C" void kernel_launch(void* const* d_in, const int* in_sizes, int n_in,
                              void* d_out, int out_size, void* d_ws, size_t ws_size,
                              hipStream_t stream) {
    const float* nf    = (const float*)d_in[0];
    const float* ef    = (const float*)d_in[1];
    const float* Wn    = (const float*)d_in[2];
    const float* Wm    = (const float*)d_in[3];
    const int*   ntype = (const int*)d_in[4];
    const int*   etype = (const int*)d_in[5];
    const int*   eidx  = (const int*)d_in[6];
    float* out = (float*)d_out;

    const size_t xout_bytes = (size_t)N_NODES * 64 * 2;        // 12.8 MB bf16
    const size_t b_bytes    = (size_t)N_NODES * KCAT * 2;      // 57.6 MB bf16

    if (ws_size >= xout_bytes + b_bytes) {
        bf16* xout = (bf16*)d_ws;
        bf16* B    = (bf16*)((char*)d_ws + xout_bytes);
        // scratch in d_out (17.6 MB < 25.6 MB); final_gemm fully overwrites
        // d_out at the end of every call.
        u64* pay      = (u64*)d_out;            // 12.8 MB
        int* cnt      = (int*)(pay + N_EDGES);  // 1.6 MB
        int* offs     = cnt + NK;               // 1.6 MB
        int* partials = offs + NK;              // 2 KB (pad 512)
        u8*  rank     = (u8*)(partials + 512);  // 1.6 MB

        zero_buf<<<400, 256, 0, stream>>>((float4*)cnt, (long)(NK / 4));
        fused_pre<<<XF_BLOCKS + CR_BLOCKS, 256, 0, stream>>>(nf, Wn, ntype, xout,
                                                             eidx, etype, cnt, rank);
        scan_a<<<NBCHUNK, 256, 0, stream>>>(cnt, partials);
        scan_b<<<1, 512, 0, stream>>>(partials);
        scan_c<<<NBCHUNK, 256, 0, stream>>>(cnt, partials, offs);
        place_pay<<<(N_EDGES + 255) / 256, 256, 0, stream>>>(eidx, etype, rank, offs, pay);
        aggregate_g<<<(N_NODES + 3) / 4, 256, 0, stream>>>(pay, offs, xout, ef, B);
        final_gemm<<<(N_NODES + 63) / 64, 256, 0, stream>>>(B, Wm, out);
    } else {
        zero_buf<<<2048, 256, 0, stream>>>((float4*)d_out, (long)((size_t)out_size * 4 / 16));
        fallback_edge<<<4096, 256, 0, stream>>>(nf, ef, Wn, Wm, ntype, etype, eidx, out);
    }
}

// Round 10
// 326.810 us; speedup vs baseline: 2.0640x; 1.1052x over previous
//
#include <hip/hip_runtime.h>
#include <hip/hip_bf16.h>

#define N_NODES 100000
#define N_EDGES 1600000
#define D_IN 64
#define D_OUT 64
#define E_DIM 32
#define KCAT 288            // 3*64 (S buckets) + 3*32 (T buckets)
#define NK (4 * N_NODES)    // sort keys: 4*dst + etype (slot 3 unused -> count 0)
#define NBCHUNK 391         // ceil(NK / 1024)

typedef unsigned long long u64;
typedef __hip_bfloat16 bf16;
typedef unsigned char u8;

// ---------------------------------------------------------------------------
// zero helper (capture-safe)
// ---------------------------------------------------------------------------
__global__ __launch_bounds__(256) void zero_buf(float4* __restrict__ p, long n4) {
    long i = (long)blockIdx.x * 256 + threadIdx.x;
    long stride = (long)gridDim.x * 256;
    float4 z = make_float4(0.f, 0.f, 0.f, 0.f);
    for (; i < n4; i += stride) p[i] = z;
}

// ---------------------------------------------------------------------------
// node_xform_g: GEMM-style microtile (64 nodes x 64 cols / block).
// Both W_node matrices staged in LDS; per-row type via float4 cndmask select.
// Replaces the shfl-per-k version (3.2 GB LDS traffic -> 1.2 GB).
// ---------------------------------------------------------------------------
__global__ __launch_bounds__(256) void node_xform_g(const float* __restrict__ nf,
                                                    const float* __restrict__ Wn,
                                                    const int* __restrict__ ntype,
                                                    bf16* __restrict__ xout) {
    __shared__ float Ws[2 * 64 * 64];   // [t][k][j], 32 KB
    __shared__ float As[64][65];        // [row][k], padded
    int tid = threadIdx.x;
    int n0 = blockIdx.x * 64;
    for (int i = tid; i < 2 * 64 * 64; i += 256) Ws[i] = Wn[i];
#pragma unroll
    for (int i = 0; i < 4; ++i) {
        int f = (i * 256 + tid) * 4;    // float index in the 64x64 tile
        int r = f >> 6, c = f & 63;
        int n = n0 + r;
        float4 v = (n < N_NODES) ? *(const float4*)&nf[(size_t)n * 64 + c]
                                 : make_float4(0.f, 0.f, 0.f, 0.f);
        As[r][c + 0] = v.x; As[r][c + 1] = v.y; As[r][c + 2] = v.z; As[r][c + 3] = v.w;
    }
    __syncthreads();
    int tx = tid & 15, ty = tid >> 4;
    int r0 = n0 + ty * 4;
    int t0 = (r0 + 0 < N_NODES) ? ntype[r0 + 0] : 0;
    int t1 = (r0 + 1 < N_NODES) ? ntype[r0 + 1] : 0;
    int t2 = (r0 + 2 < N_NODES) ? ntype[r0 + 2] : 0;
    int t3 = (r0 + 3 < N_NODES) ? ntype[r0 + 3] : 0;
    float4 acc0 = {0,0,0,0}, acc1 = {0,0,0,0}, acc2 = {0,0,0,0}, acc3 = {0,0,0,0};
#pragma unroll 8
    for (int k = 0; k < 64; ++k) {
        float4 w0 = *(const float4*)&Ws[k * 64 + tx * 4];
        float4 w1 = *(const float4*)&Ws[4096 + k * 64 + tx * 4];
        float a0 = As[ty * 4 + 0][k];
        float a1 = As[ty * 4 + 1][k];
        float a2 = As[ty * 4 + 2][k];
        float a3 = As[ty * 4 + 3][k];
        float4 wa = t0 ? w1 : w0;
        float4 wb = t1 ? w1 : w0;
        float4 wc = t2 ? w1 : w0;
        float4 wd = t3 ? w1 : w0;
        acc0.x = fmaf(a0, wa.x, acc0.x); acc0.y = fmaf(a0, wa.y, acc0.y);
        acc0.z = fmaf(a0, wa.z, acc0.z); acc0.w = fmaf(a0, wa.w, acc0.w);
        acc1.x = fmaf(a1, wb.x, acc1.x); acc1.y = fmaf(a1, wb.y, acc1.y);
        acc1.z = fmaf(a1, wb.z, acc1.z); acc1.w = fmaf(a1, wb.w, acc1.w);
        acc2.x = fmaf(a2, wc.x, acc2.x); acc2.y = fmaf(a2, wc.y, acc2.y);
        acc2.z = fmaf(a2, wc.z, acc2.z); acc2.w = fmaf(a2, wc.w, acc2.w);
        acc3.x = fmaf(a3, wd.x, acc3.x); acc3.y = fmaf(a3, wd.y, acc3.y);
        acc3.z = fmaf(a3, wd.z, acc3.z); acc3.w = fmaf(a3, wd.w, acc3.w);
    }
#pragma unroll
    for (int r = 0; r < 4; ++r) {
        int n = r0 + r;
        if (n < N_NODES) {
            float4 a = (r == 0) ? acc0 : (r == 1) ? acc1 : (r == 2) ? acc2 : acc3;
            union { bf16 h[4]; uint2 u; } pk;
            pk.h[0] = __float2bfloat16(a.x); pk.h[1] = __float2bfloat16(a.y);
            pk.h[2] = __float2bfloat16(a.z); pk.h[3] = __float2bfloat16(a.w);
            *(uint2*)&xout[(size_t)n * 64 + tx * 4] = pk.u;
        }
    }
}

// ---------------------------------------------------------------------------
// count + rank: rank[i] = arrival order within key (4*dst+etype).
// ---------------------------------------------------------------------------
__global__ __launch_bounds__(256) void count_rank(const int* __restrict__ eidx,
                                                  const int* __restrict__ etype,
                                                  int* __restrict__ cnt,
                                                  u8* __restrict__ rank) {
    int i = blockIdx.x * 256 + threadIdx.x;   // edge quad id
    if (i >= N_EDGES / 4) return;
    int4 d = ((const int4*)(eidx + N_EDGES))[i];
    int4 t = ((const int4*)etype)[i];
    int r0 = atomicAdd(&cnt[4 * d.x + t.x], 1);
    int r1 = atomicAdd(&cnt[4 * d.y + t.y], 1);
    int r2 = atomicAdd(&cnt[4 * d.z + t.z], 1);
    int r3 = atomicAdd(&cnt[4 * d.w + t.w], 1);
    ((uchar4*)rank)[i] = make_uchar4((u8)r0, (u8)r1, (u8)r2, (u8)r3);
}

__global__ __launch_bounds__(256) void scan_a(const int* __restrict__ cnt,
                                              int* __restrict__ partials) {
    __shared__ int ws[4];
    int b = blockIdx.x, tid = threadIdx.x, lane = tid & 63, wid = tid >> 6;
    int i0 = b * 1024 + tid * 4;
    int s = 0;
#pragma unroll
    for (int k = 0; k < 4; ++k) { int i = i0 + k; if (i < NK) s += cnt[i]; }
#pragma unroll
    for (int d = 32; d > 0; d >>= 1) s += __shfl_down(s, d);
    if (lane == 0) ws[wid] = s;
    __syncthreads();
    if (tid == 0) partials[b] = ws[0] + ws[1] + ws[2] + ws[3];
}

__global__ __launch_bounds__(512) void scan_b(int* __restrict__ partials) {
    __shared__ int s[512];
    int tid = threadIdx.x;
    int v = (tid < NBCHUNK) ? partials[tid] : 0;
    s[tid] = v;
    __syncthreads();
    for (int d = 1; d < 512; d <<= 1) {
        int u = (tid >= d) ? s[tid - d] : 0;
        __syncthreads();
        s[tid] += u;
        __syncthreads();
    }
    if (tid < NBCHUNK) partials[tid] = s[tid] - v;   // exclusive
}

__global__ __launch_bounds__(256) void scan_c(const int* __restrict__ cnt,
                                              const int* __restrict__ partials,
                                              int* __restrict__ offs) {
    __shared__ int wsum[4];
    int b = blockIdx.x, tid = threadIdx.x, lane = tid & 63, wid = tid >> 6;
    int i0 = b * 1024 + tid * 4;
    int c0 = (i0 + 0 < NK) ? cnt[i0 + 0] : 0;
    int c1 = (i0 + 1 < NK) ? cnt[i0 + 1] : 0;
    int c2 = (i0 + 2 < NK) ? cnt[i0 + 2] : 0;
    int c3 = (i0 + 3 < NK) ? cnt[i0 + 3] : 0;
    int lsum = c0 + c1 + c2 + c3;
    int v = lsum;
#pragma unroll
    for (int d = 1; d < 64; d <<= 1) {
        int u = __shfl_up(v, d);
        if (lane >= d) v += u;
    }
    int wexcl = v - lsum;
    if (lane == 63) wsum[wid] = v;
    __syncthreads();
    int bexcl = 0;
    for (int w = 0; w < wid; ++w) bexcl += wsum[w];
    int base = partials[b] + bexcl + wexcl;
    if (i0 + 0 < NK) offs[i0 + 0] = base; base += c0;
    if (i0 + 1 < NK) offs[i0 + 1] = base; base += c1;
    if (i0 + 2 < NK) offs[i0 + 2] = base; base += c2;
    if (i0 + 3 < NK) offs[i0 + 3] = base;
}

// ---------------------------------------------------------------------------
// place_pay: 8B payload scatter (pos = offs[key]+rank, no atomics).
// ---------------------------------------------------------------------------
__global__ __launch_bounds__(256) void place_pay(const int* __restrict__ eidx,
                                                 const int* __restrict__ etype,
                                                 const u8* __restrict__ rank,
                                                 const int* __restrict__ offs,
                                                 u64* __restrict__ pay) {
    int i = blockIdx.x * 256 + threadIdx.x;
    if (i >= N_EDGES) return;
    int d = eidx[N_EDGES + i];
    int s = eidx[i];
    int t = etype[i];
    int pos = offs[4 * d + t] + (int)rank[i];
    pay[pos] = (u64)(unsigned)s | ((u64)(unsigned)i << 32);
}

// ---------------------------------------------------------------------------
// aggregate_g: wave/node; 8 xout row-gathers + 4 full-wave ef gathers per
// 8 edges, all independent. Guarded accumulate. Zero atomics.
// ---------------------------------------------------------------------------
__global__ __launch_bounds__(256) void aggregate_g(const u64* __restrict__ pay,
                                                   const int* __restrict__ offs,
                                                   const bf16* __restrict__ xout,
                                                   const float* __restrict__ ef,
                                                   bf16* __restrict__ B) {
    int wid = threadIdx.x >> 6, lane = threadIdx.x & 63;
    int n = blockIdx.x * 4 + wid;
    if (n >= N_NODES) return;
    int4 o = ((const int4*)offs)[n];           // starts t0,t1,t2, end
    int beg = __builtin_amdgcn_readfirstlane(o.x);
    int y   = __builtin_amdgcn_readfirstlane(o.y);
    int z   = __builtin_amdgcn_readfirstlane(o.z);
    int end = __builtin_amdgcn_readfirstlane(o.w);
    float a0 = 0.f, a1 = 0.f, a2 = 0.f, b0 = 0.f, b1 = 0.f, b2 = 0.f;
    int col = lane & 31, half = lane >> 5;

    for (int base = beg; base < end; base += 64) {
        int m = end - base; if (m > 64) m = 64;
        u64 p = (lane < m) ? pay[base + lane] : 0ull;
        int plo = (int)(unsigned)p;            // src
        int phi = (int)(unsigned)(p >> 32);    // edge id
        for (int j = 0; j < m; j += 8) {
            int s0 = __builtin_amdgcn_readlane(plo, j + 0);
            int s1 = __builtin_amdgcn_readlane(plo, j + 1);
            int s2 = __builtin_amdgcn_readlane(plo, j + 2);
            int s3 = __builtin_amdgcn_readlane(plo, j + 3);
            int s4 = __builtin_amdgcn_readlane(plo, j + 4);
            int s5 = __builtin_amdgcn_readlane(plo, j + 5);
            int s6 = __builtin_amdgcn_readlane(plo, j + 6);
            int s7 = __builtin_amdgcn_readlane(plo, j + 7);
            int e0 = __builtin_amdgcn_readlane(phi, j + 0);
            int e1 = __builtin_amdgcn_readlane(phi, j + 1);
            int e2 = __builtin_amdgcn_readlane(phi, j + 2);
            int e3 = __builtin_amdgcn_readlane(phi, j + 3);
            int e4 = __builtin_amdgcn_readlane(phi, j + 4);
            int e5 = __builtin_amdgcn_readlane(phi, j + 5);
            int e6 = __builtin_amdgcn_readlane(phi, j + 6);
            int e7 = __builtin_amdgcn_readlane(phi, j + 7);
            float x0 = __bfloat162float(xout[(size_t)s0 * 64 + lane]);
            float x1 = __bfloat162float(xout[(size_t)s1 * 64 + lane]);
            float x2 = __bfloat162float(xout[(size_t)s2 * 64 + lane]);
            float x3 = __bfloat162float(xout[(size_t)s3 * 64 + lane]);
            float x4 = __bfloat162float(xout[(size_t)s4 * 64 + lane]);
            float x5 = __bfloat162float(xout[(size_t)s5 * 64 + lane]);
            float x6 = __bfloat162float(xout[(size_t)s6 * 64 + lane]);
            float x7 = __bfloat162float(xout[(size_t)s7 * 64 + lane]);
            int r0_ = half ? e1 : e0;
            int r1_ = half ? e3 : e2;
            int r2_ = half ? e5 : e4;
            int r3_ = half ? e7 : e6;
            float v0 = ef[(size_t)r0_ * 32 + col];
            float v1 = ef[(size_t)r1_ * 32 + col];
            float v2 = ef[(size_t)r2_ * 32 + col];
            float v3 = ef[(size_t)r3_ * 32 + col];
#pragma unroll
            for (int k = 0; k < 8; ++k) {
                int idx = base + j + k;
                float xv = (k == 0) ? x0 : (k == 1) ? x1 : (k == 2) ? x2 : (k == 3) ? x3
                         : (k == 4) ? x4 : (k == 5) ? x5 : (k == 6) ? x6 : x7;
                if (idx < y)        a0 += xv;
                else if (idx < z)   a1 += xv;
                else if (idx < end) a2 += xv;
            }
#pragma unroll
            for (int q = 0; q < 4; ++q) {
                float vv = (q == 0) ? v0 : (q == 1) ? v1 : (q == 2) ? v2 : v3;
                int idx = base + j + 2 * q + half;
                vv = (idx < end) ? vv : 0.f;
                float c0_ = (idx < y)  ? vv : 0.f;
                float c2_ = (idx >= z) ? vv : 0.f;
                b0 += c0_; b2 += c2_; b1 += vv - c0_ - c2_;
            }
        }
    }
    b0 += __shfl_down(b0, 32);
    b1 += __shfl_down(b1, 32);
    b2 += __shfl_down(b2, 32);

    bf16* Bn = B + (size_t)n * KCAT;
    Bn[lane]       = __float2bfloat16(a0);
    Bn[64 + lane]  = __float2bfloat16(a1);
    Bn[128 + lane] = __float2bfloat16(a2);
    if (lane < 32) {
        Bn[192 + lane] = __float2bfloat16(b0);
        Bn[224 + lane] = __float2bfloat16(b1);
        Bn[256 + lane] = __float2bfloat16(b2);
    }
}

// ---------------------------------------------------------------------------
// K3: out = B(bf16) @ Wcat(fp32), Wcat[288][64] remapped from W_msg on load.
// ---------------------------------------------------------------------------
__global__ __launch_bounds__(256) void final_gemm(const bf16* __restrict__ B,
                                                  const float* __restrict__ Wm,
                                                  float* __restrict__ out) {
    __shared__ float As[64][33];   // +1 pad
    __shared__ float Ws[32][64];
    int tid = threadIdx.x;
    int n0 = blockIdx.x * 64;
    int tx = tid & 15;
    int ty = tid >> 4;
    float acc[4][4] = {};

    for (int k0 = 0; k0 < KCAT; k0 += 32) {
#pragma unroll
        for (int i = 0; i < 8; ++i) {
            int f = i * 256 + tid;
            int r = f >> 5, cc = f & 31;
            int n = n0 + r;
            As[r][cc] = (n < N_NODES) ? __bfloat162float(B[(size_t)n * KCAT + k0 + cc]) : 0.f;
        }
#pragma unroll
        for (int i = 0; i < 8; ++i) {
            int f = i * 256 + tid;
            int kk = f >> 6, j = f & 63;
            int r = k0 + kk;
            int t, kin;
            if (r < 192) { t = r >> 6; kin = r & 63; }
            else         { int q = r - 192; t = q >> 5; kin = 64 + (q & 31); }
            Ws[kk][j] = Wm[(t * 96 + kin) * 64 + j];
        }
        __syncthreads();
#pragma unroll
        for (int kk = 0; kk < 32; ++kk) {
            float a0 = As[ty * 4 + 0][kk];
            float a1 = As[ty * 4 + 1][kk];
            float a2 = As[ty * 4 + 2][kk];
            float a3 = As[ty * 4 + 3][kk];
            float4 w = *(const float4*)&Ws[kk][tx * 4];
            acc[0][0] = fmaf(a0, w.x, acc[0][0]); acc[0][1] = fmaf(a0, w.y, acc[0][1]);
            acc[0][2] = fmaf(a0, w.z, acc[0][2]); acc[0][3] = fmaf(a0, w.w, acc[0][3]);
            acc[1][0] = fmaf(a1, w.x, acc[1][0]); acc[1][1] = fmaf(a1, w.y, acc[1][1]);
            acc[1][2] = fmaf(a1, w.z, acc[1][2]); acc[1][3] = fmaf(a1, w.w, acc[1][3]);
            acc[2][0] = fmaf(a2, w.x, acc[2][0]); acc[2][1] = fmaf(a2, w.y, acc[2][1]);
            acc[2][2] = fmaf(a2, w.z, acc[2][2]); acc[2][3] = fmaf(a2, w.w, acc[2][3]);
            acc[3][0] = fmaf(a3, w.x, acc[3][0]); acc[3][1] = fmaf(a3, w.y, acc[3][1]);
            acc[3][2] = fmaf(a3, w.z, acc[3][2]); acc[3][3] = fmaf(a3, w.w, acc[3][3]);
        }
        __syncthreads();
    }
#pragma unroll
    for (int r = 0; r < 4; ++r) {
        int n = n0 + ty * 4 + r;
        if (n < N_NODES) {
            float4 v = make_float4(acc[r][0], acc[r][1], acc[r][2], acc[r][3]);
            *(float4*)&out[(size_t)n * 64 + tx * 4] = v;
        }
    }
}

// ---------------------------------------------------------------------------
// Fallback (ws tiny): direct wave-per-edge, fp32.
// ---------------------------------------------------------------------------
__global__ __launch_bounds__(256) void fallback_edge(const float* __restrict__ nf,
                                                     const float* __restrict__ ef,
                                                     const float* __restrict__ Wn,
                                                     const float* __restrict__ Wm,
                                                     const int* __restrict__ ntype,
                                                     const int* __restrict__ etype,
                                                     const int* __restrict__ eidx,
                                                     float* __restrict__ out) {
    __shared__ float wn[2 * 64 * 64];
    __shared__ float wm[3 * 96 * 64];
    for (int i = threadIdx.x; i < 2 * 64 * 64; i += 256) wn[i] = Wn[i];
    for (int i = threadIdx.x; i < 3 * 96 * 64; i += 256) wm[i] = Wm[i];
    __syncthreads();
    int wid = threadIdx.x >> 6, lane = threadIdx.x & 63;
    for (int e = blockIdx.x * 4 + wid; e < N_EDGES; e += gridDim.x * 4) {
        int t = etype[e];
        int s = eidx[e];
        int d = eidx[N_EDGES + e];
        int nt = ntype[s];
        float xs = nf[(long)s * 64 + lane];
        const float* wcol = &wn[nt * 4096 + lane];
        float xo = 0.f;
#pragma unroll 16
        for (int k = 0; k < 64; ++k) xo = fmaf(__shfl(xs, k), wcol[k * 64], xo);
        float ev = ef[(long)e * 32 + (lane & 31)];
        const float* mcol = &wm[t * 96 * 64 + lane];
        float m = 0.f;
#pragma unroll 16
        for (int k = 0; k < 64; ++k) m = fmaf(__shfl(xo, k), mcol[k * 64], m);
#pragma unroll 8
        for (int k = 0; k < 32; ++k) m = fmaf(__shfl(ev, k), mcol[(64 + k) * 64], m);
        atomicAdd(&out[(long)d * 64 + lane], m);
    }
}

// ---------------------------------------------------------------------------
extern "C" void kernel_launch(void* const* d_in, const int* in_sizes, int n_in,
                              void* d_out, int out_size, void* d_ws, size_t ws_size,
                              hipStream_t stream) {
    const float* nf    = (const float*)d_in[0];
    const float* ef    = (const float*)d_in[1];
    const float* Wn    = (const float*)d_in[2];
    const float* Wm    = (const float*)d_in[3];
    const int*   ntype = (const int*)d_in[4];
    const int*   etype = (const int*)d_in[5];
    const int*   eidx  = (const int*)d_in[6];
    float* out = (float*)d_out;

    const size_t xout_bytes = (size_t)N_NODES * 64 * 2;        // 12.8 MB bf16
    const size_t b_bytes    = (size_t)N_NODES * KCAT * 2;      // 57.6 MB bf16

    if (ws_size >= xout_bytes + b_bytes) {
        bf16* xout = (bf16*)d_ws;
        bf16* B    = (bf16*)((char*)d_ws + xout_bytes);
        // scratch in d_out (17.6 MB < 25.6 MB); final_gemm fully overwrites
        // d_out at the end of every call.
        u64* pay      = (u64*)d_out;            // 12.8 MB
        int* cnt      = (int*)(pay + N_EDGES);  // 1.6 MB
        int* offs     = cnt + NK;               // 1.6 MB
        int* partials = offs + NK;              // 2 KB (pad 512)
        u8*  rank     = (u8*)(partials + 512);  // 1.6 MB

        zero_buf<<<400, 256, 0, stream>>>((float4*)cnt, (long)(NK / 4));
        node_xform_g<<<(N_NODES + 63) / 64, 256, 0, stream>>>(nf, Wn, ntype, xout);
        count_rank<<<(N_EDGES / 4 + 255) / 256, 256, 0, stream>>>(eidx, etype, cnt, rank);
        scan_a<<<NBCHUNK, 256, 0, stream>>>(cnt, partials);
        scan_b<<<1, 512, 0, stream>>>(partials);
        scan_c<<<NBCHUNK, 256, 0, stream>>>(cnt, partials, offs);
        place_pay<<<(N_EDGES + 255) / 256, 256, 0, stream>>>(eidx, etype, rank, offs, pay);
        aggregate_g<<<(N_NODES + 3) / 4, 256, 0, stream>>>(pay, offs, xout, ef, B);
        final_gemm<<<(N_NODES + 63) / 64, 256, 0, stream>>>(B, Wm, out);
    } else {
        zero_buf<<<2048, 256, 0, stream>>>((float4*)d_out, (long)((size_t)out_size * 4 / 16));
        fallback_edge<<<4096, 256, 0, stream>>>(nf, ef, Wn, Wm, ntype, etype, eidx, out);
    }
}